// Round 2
// baseline (456.577 us; speedup 1.0000x reference)
//
#include <hip/hip_runtime.h>
#include <math.h>

// ---------------------------------------------------------------------------
// GAU-alpha fused block for MI355X (gfx950).
// B=64, S=512, H=512, E=1024, UV=2176, D=128, M=B*S=32768.
// bf16 MFMA (16x16x32) for all 4 matmuls, fp32 elsewhere.
// Workspace budget ~196 MiB (round-1 crash diagnosed as ws overflow at ~260):
//   - v is produced directly in transposed (b,e,s) layout by gemm1's epilogue
//     (LDS tile transpose), so no separate v buffer / transpose kernel.
//   - PV epilogue multiplies u in place (oe aliases u).
// ---------------------------------------------------------------------------

#define M_TOT   32768
#define S_LEN   512
#define H_DIM   512
#define E_DIMC  1024
#define UV_DIM  2176
#define D_DIM   128

using floatx4  = __attribute__((ext_vector_type(4))) float;
using uintx2   = __attribute__((ext_vector_type(2))) unsigned int;
using uintx4   = __attribute__((ext_vector_type(4))) unsigned int;
using ushortx4 = __attribute__((ext_vector_type(4))) unsigned short;
using short8   = __attribute__((ext_vector_type(8))) short;

__device__ __forceinline__ float bf2f(unsigned short h) {
    union { unsigned int u; float f; } c;
    c.u = ((unsigned int)h) << 16;
    return c.f;
}
__device__ __forceinline__ unsigned short f2bf(float f) {
    union { float f; unsigned int u; } c;
    c.f = f;
    unsigned int r = c.u + 0x7fffu + ((c.u >> 16) & 1u);  // RNE
    return (unsigned short)(r >> 16);
}

// ---------------------------------------------------------------------------
__global__ __launch_bounds__(256) void f2bf_kernel(const float* __restrict__ in,
                                                   unsigned short* __restrict__ out,
                                                   int n4) {
    int i = blockIdx.x * 256 + threadIdx.x;
    if (i < n4) {
        floatx4 v = ((const floatx4*)in)[i];
        ushortx4 o;
        o.x = f2bf(v.x); o.y = f2bf(v.y); o.z = f2bf(v.z); o.w = f2bf(v.w);
        ((ushortx4*)out)[i] = o;
    }
}

// ---------------------------------------------------------------------------
__global__ __launch_bounds__(256) void rmsnorm_kernel(const float* __restrict__ x,
                                                      const float* __restrict__ ln_g,
                                                      unsigned short* __restrict__ xn) {
    int row  = blockIdx.x * 4 + (threadIdx.x >> 6);
    int lane = threadIdx.x & 63;
    const float* xr = x + (size_t)row * H_DIM;
    floatx4 v0 = ((const floatx4*)xr)[lane];
    floatx4 v1 = ((const floatx4*)xr)[lane + 64];
    float ss = v0.x*v0.x + v0.y*v0.y + v0.z*v0.z + v0.w*v0.w
             + v1.x*v1.x + v1.y*v1.y + v1.z*v1.z + v1.w*v1.w;
    #pragma unroll
    for (int off = 32; off > 0; off >>= 1) ss += __shfl_xor(ss, off, 64);
    float norm = sqrtf(ss) * 0.044194173824159216f;  // * H^-0.5
    float sc   = ln_g[0] / fmaxf(norm, 1e-5f);
    unsigned short* xo = xn + (size_t)row * H_DIM;
    ushortx4 o0, o1;
    o0.x = f2bf(v0.x * sc); o0.y = f2bf(v0.y * sc);
    o0.z = f2bf(v0.z * sc); o0.w = f2bf(v0.w * sc);
    o1.x = f2bf(v1.x * sc); o1.y = f2bf(v1.y * sc);
    o1.z = f2bf(v1.z * sc); o1.w = f2bf(v1.w * sc);
    ((ushortx4*)xo)[lane]      = o0;
    ((ushortx4*)xo)[lane + 64] = o1;
}

// ---------------------------------------------------------------------------
// RoPE tables — mimic fp32 numpy: inv_freq = powf-rounded fp32, angle = fp32
// product, sin/cos correctly rounded of that exact fp32 argument.
// ---------------------------------------------------------------------------
__global__ __launch_bounds__(64) void rope_table_kernel(float* __restrict__ cost,
                                                        float* __restrict__ sint) {
    int s = blockIdx.x;
    int j = threadIdx.x;  // 0..63
    float invf = (float)pow(10000.0, (double)j / 64.0);
    float ang  = (float)s * invf;  // fp32 multiply like the f32 reference
    double a   = (double)ang;
    cost[s * 64 + j] = (float)cos(a);
    sint[s * 64 + j] = (float)sin(a);
}

// ---------------------------------------------------------------------------
__global__ __launch_bounds__(256) void rope_apply_kernel(const float* __restrict__ base,
                                                         const float* __restrict__ gamma,
                                                         const float* __restrict__ beta,
                                                         const float* __restrict__ cost,
                                                         const float* __restrict__ sint,
                                                         unsigned short* __restrict__ q,
                                                         unsigned short* __restrict__ k) {
    int idx = blockIdx.x * 256 + threadIdx.x;  // M*64 total
    int m = idx >> 6;
    int j = idx & 63;
    int s = m & (S_LEN - 1);
    float b1 = base[(size_t)m * D_DIM + j];
    float b2 = base[(size_t)m * D_DIM + 64 + j];
    float c  = cost[s * 64 + j];
    float sn = sint[s * 64 + j];
    float yq1 = b1 * gamma[j]       + beta[j];
    float yq2 = b2 * gamma[64 + j]  + beta[64 + j];
    float yk1 = b1 * gamma[128 + j] + beta[128 + j];
    float yk2 = b2 * gamma[192 + j] + beta[192 + j];
    q[(size_t)m * D_DIM + j]      = f2bf(yq1 * c - yq2 * sn);
    q[(size_t)m * D_DIM + 64 + j] = f2bf(yq2 * c + yq1 * sn);
    k[(size_t)m * D_DIM + j]      = f2bf(yk1 * c - yk2 * sn);
    k[(size_t)m * D_DIM + 64 + j] = f2bf(yk2 * c + yk1 * sn);
}

// ---------------------------------------------------------------------------
// GEMM core, B^T form: C[m][n] = sum_k A[m][k]*B[n][k], A/B bf16 row-major.
// 128x128 tile, 256 threads (4 waves, 2x2 of 64x64), 16x16x32 bf16 MFMA,
// BK=64, LDS pitch 72. Fragment layouts (HW-verified per guide):
//   A: A[m = lane&15][k = (lane>>4)*8 + j]
//   B: B-row n = lane&15, k = (lane>>4)*8 + j
//   C: col = lane&15, row = (lane>>4)*4 + reg
// ---------------------------------------------------------------------------
struct GemmLds {
    unsigned short As[128 * 72];
    unsigned short Bs[128 * 72];
};

__device__ __forceinline__ void gemm_bt_core(const unsigned short* __restrict__ A,
                                             const unsigned short* __restrict__ B,
                                             int lda, int ldb, int K,
                                             int m0, int n0,
                                             GemmLds& lds, floatx4 (&acc)[4][4]) {
    const int tid  = threadIdx.x;
    const int lane = tid & 63;
    const int wave = tid >> 6;
    const int quad = lane >> 4;
    const int l16  = lane & 15;
    const int wm   = (wave >> 1) * 64;
    const int wn   = (wave & 1) * 64;

    #pragma unroll
    for (int i = 0; i < 4; i++)
        #pragma unroll
        for (int j = 0; j < 4; j++) acc[i][j] = (floatx4){0.f, 0.f, 0.f, 0.f};

    for (int kt = 0; kt < K; kt += 64) {
        #pragma unroll
        for (int i = 0; i < 4; i++) {
            int c  = tid + i * 256;     // 0..1023
            int r  = c >> 3;            // 0..127
            int c8 = (c & 7) * 8;       // 0..56
            uintx4 av = *(const uintx4*)(A + (size_t)(m0 + r) * lda + kt + c8);
            uintx4 bv = *(const uintx4*)(B + (size_t)(n0 + r) * ldb + kt + c8);
            *(uintx2*)&lds.As[r * 72 + c8]     = (uintx2){av.x, av.y};
            *(uintx2*)&lds.As[r * 72 + c8 + 4] = (uintx2){av.z, av.w};
            *(uintx2*)&lds.Bs[r * 72 + c8]     = (uintx2){bv.x, bv.y};
            *(uintx2*)&lds.Bs[r * 72 + c8 + 4] = (uintx2){bv.z, bv.w};
        }
        __syncthreads();
        #pragma unroll
        for (int kk = 0; kk < 64; kk += 32) {
            short8 af[4], bf[4];
            #pragma unroll
            for (int mt = 0; mt < 4; mt++) {
                const unsigned short* p = &lds.As[(wm + mt * 16 + l16) * 72 + kk + quad * 8];
                union { short8 s8; uintx2 u2[2]; } fu;
                fu.u2[0] = *(const uintx2*)p;
                fu.u2[1] = *(const uintx2*)(p + 4);
                af[mt] = fu.s8;
            }
            #pragma unroll
            for (int nt = 0; nt < 4; nt++) {
                const unsigned short* p = &lds.Bs[(wn + nt * 16 + l16) * 72 + kk + quad * 8];
                union { short8 s8; uintx2 u2[2]; } fu;
                fu.u2[0] = *(const uintx2*)p;
                fu.u2[1] = *(const uintx2*)(p + 4);
                bf[nt] = fu.s8;
            }
            #pragma unroll
            for (int mt = 0; mt < 4; mt++)
                #pragma unroll
                for (int nt = 0; nt < 4; nt++)
                    acc[mt][nt] = __builtin_amdgcn_mfma_f32_16x16x32_bf16(
                        af[mt], bf[nt], acc[mt][nt], 0, 0, 0);
        }
        __syncthreads();
    }
}

// ---------------------------------------------------------------------------
// GEMM1: act = silu(xn @ uv_w^T + uv_b).
//   blockIdx.y <  8 : u columns, write u (m,e) bf16
//   blockIdx.y 8..15: v columns, LDS-transpose tile, write vT (b,e,s) bf16
//   blockIdx.y == 16: base columns, write fp32
// ---------------------------------------------------------------------------
__global__ __launch_bounds__(256) void gemm1_kernel(const unsigned short* __restrict__ xn,
                                                    const unsigned short* __restrict__ uvw,
                                                    const float* __restrict__ uvb,
                                                    unsigned short* __restrict__ u,
                                                    unsigned short* __restrict__ vT,
                                                    float* __restrict__ base) {
    __shared__ union LdsU {
        GemmLds g;
        unsigned short T[128 * 136];   // 34816 B <= sizeof(GemmLds)=36864 B
    } lds;
    floatx4 acc[4][4];
    const int m0 = blockIdx.x * 128, n0 = blockIdx.y * 128;
    gemm_bt_core(xn, uvw, H_DIM, H_DIM, H_DIM, m0, n0, lds.g, acc);

    const int tid  = threadIdx.x;
    const int lane = tid & 63;
    const int wave = tid >> 6;
    const int quad = lane >> 4;
    const int l16  = lane & 15;
    const int wm   = (wave >> 1) * 64;
    const int wn   = (wave & 1) * 64;

    if (blockIdx.y < 8) {
        #pragma unroll
        for (int mt = 0; mt < 4; mt++)
            #pragma unroll
            for (int nt = 0; nt < 4; nt++)
                #pragma unroll
                for (int r = 0; r < 4; r++) {
                    int m = m0 + wm + mt * 16 + quad * 4 + r;
                    int n = n0 + wn + nt * 16 + l16;
                    float val = acc[mt][nt][r] + uvb[n];
                    u[(size_t)m * E_DIMC + n] = f2bf(val / (1.0f + expf(-val)));
                }
    } else if (blockIdx.y == 16) {
        #pragma unroll
        for (int mt = 0; mt < 4; mt++)
            #pragma unroll
            for (int nt = 0; nt < 4; nt++)
                #pragma unroll
                for (int r = 0; r < 4; r++) {
                    int m = m0 + wm + mt * 16 + quad * 4 + r;
                    int n = n0 + wn + nt * 16 + l16;
                    float val = acc[mt][nt][r] + uvb[n];
                    base[(size_t)m * D_DIM + (n - 2 * E_DIMC)] = val / (1.0f + expf(-val));
                }
    } else {
        // v tile: transpose through LDS (core's trailing __syncthreads makes
        // As/Bs reuse safe), then coalesced store to vT (b, e, s).
        #pragma unroll
        for (int mt = 0; mt < 4; mt++)
            #pragma unroll
            for (int nt = 0; nt < 4; nt++)
                #pragma unroll
                for (int r = 0; r < 4; r++) {
                    int ml = wm + mt * 16 + quad * 4 + r;     // local m (s)
                    int nl = wn + nt * 16 + l16;              // local n (e)
                    float val = acc[mt][nt][r] + uvb[n0 + nl];
                    lds.T[nl * 136 + ml] = f2bf(val / (1.0f + expf(-val)));
                }
        __syncthreads();
        const int b   = m0 >> 9;           // 128-row tile lies in one batch
        const int sg0 = m0 & (S_LEN - 1);
        const int eg0 = n0 - E_DIMC;       // n0 in [1024,2048)
        #pragma unroll
        for (int i = 0; i < 8; i++) {
            int idx = tid + i * 256;       // 0..2047
            int e   = idx >> 4;            // 0..127
            int s8  = (idx & 15) * 8;      // 0..120
            uintx4 val = *(const uintx4*)&lds.T[e * 136 + s8];
            *(uintx4*)(vT + ((size_t)b * E_DIMC + eg0 + e) * S_LEN + sg0 + s8) = val;
        }
    }
}

// ---------------------------------------------------------------------------
// qk GEMM (batched over b): P = relu((q k^T + w_bias)/sqrt(128))^2, bf16
// ---------------------------------------------------------------------------
__global__ __launch_bounds__(256) void gemm_qk_kernel(const unsigned short* __restrict__ q,
                                                      const unsigned short* __restrict__ k,
                                                      const float* __restrict__ wbias,
                                                      unsigned short* __restrict__ P) {
    __shared__ GemmLds lds;
    floatx4 acc[4][4];
    size_t boff = (size_t)blockIdx.z * S_LEN * D_DIM;
    unsigned short* Pb = P + (size_t)blockIdx.z * S_LEN * S_LEN;
    const int m0 = blockIdx.x * 128, n0 = blockIdx.y * 128;
    gemm_bt_core(q + boff, k + boff, D_DIM, D_DIM, D_DIM, m0, n0, lds, acc);

    const int tid = threadIdx.x, lane = tid & 63, wave = tid >> 6;
    const int quad = lane >> 4, l16 = lane & 15;
    const int wm = (wave >> 1) * 64, wn = (wave & 1) * 64;
    #pragma unroll
    for (int mt = 0; mt < 4; mt++)
        #pragma unroll
        for (int nt = 0; nt < 4; nt++)
            #pragma unroll
            for (int r = 0; r < 4; r++) {
                int s = m0 + wm + mt * 16 + quad * 4 + r;
                int t = n0 + wn + nt * 16 + l16;
                float z = (acc[mt][nt][r] + wbias[t - s + (S_LEN - 1)]) * 0.08838834764831845f;
                z = fmaxf(z, 0.f);
                Pb[(size_t)s * S_LEN + t] = f2bf(z * z);
            }
}

// ---------------------------------------------------------------------------
// PV GEMM (batched): u <- u .* (P @ v)  [in place; each element touched once]
// ---------------------------------------------------------------------------
__global__ __launch_bounds__(256) void gemm_pv_kernel(const unsigned short* __restrict__ P,
                                                      const unsigned short* __restrict__ vT,
                                                      unsigned short* __restrict__ u) {
    __shared__ GemmLds lds;
    floatx4 acc[4][4];
    int bb = blockIdx.z;
    const unsigned short* Pb  = P  + (size_t)bb * S_LEN * S_LEN;
    const unsigned short* vTb = vT + (size_t)bb * E_DIMC * S_LEN;
    const int m0 = blockIdx.x * 128, n0 = blockIdx.y * 128;
    gemm_bt_core(Pb, vTb, S_LEN, S_LEN, S_LEN, m0, n0, lds, acc);

    const int tid = threadIdx.x, lane = tid & 63, wave = tid >> 6;
    const int quad = lane >> 4, l16 = lane & 15;
    const int wm = (wave >> 1) * 64, wn = (wave & 1) * 64;
    #pragma unroll
    for (int mt = 0; mt < 4; mt++)
        #pragma unroll
        for (int nt = 0; nt < 4; nt++)
            #pragma unroll
            for (int r = 0; r < 4; r++) {
                int s = m0 + wm + mt * 16 + quad * 4 + r;
                int e = n0 + wn + nt * 16 + l16;
                size_t off = ((size_t)bb * S_LEN + s) * E_DIMC + e;
                u[off] = f2bf(acc[mt][nt][r] * bf2f(u[off]));
            }
}

// ---------------------------------------------------------------------------
// Output GEMM: out = oe @ o_w^T + o_b + x   (fp32 out; oe aliases u)
// ---------------------------------------------------------------------------
__global__ __launch_bounds__(256) void gemm_out_kernel(const unsigned short* __restrict__ oe,
                                                       const unsigned short* __restrict__ ow,
                                                       const float* __restrict__ ob,
                                                       const float* __restrict__ x,
                                                       float* __restrict__ out) {
    __shared__ GemmLds lds;
    floatx4 acc[4][4];
    const int m0 = blockIdx.x * 128, n0 = blockIdx.y * 128;
    gemm_bt_core(oe, ow, E_DIMC, E_DIMC, E_DIMC, m0, n0, lds, acc);

    const int tid = threadIdx.x, lane = tid & 63, wave = tid >> 6;
    const int quad = lane >> 4, l16 = lane & 15;
    const int wm = (wave >> 1) * 64, wn = (wave & 1) * 64;
    #pragma unroll
    for (int mt = 0; mt < 4; mt++)
        #pragma unroll
        for (int nt = 0; nt < 4; nt++)
            #pragma unroll
            for (int r = 0; r < 4; r++) {
                int m = m0 + wm + mt * 16 + quad * 4 + r;
                int n = n0 + wn + nt * 16 + l16;
                size_t off = (size_t)m * H_DIM + n;
                out[off] = acc[mt][nt][r] + ob[n] + x[off];
            }
}

// ---------------------------------------------------------------------------
extern "C" void kernel_launch(void* const* d_in, const int* in_sizes, int n_in,
                              void* d_out, int out_size, void* d_ws, size_t ws_size,
                              hipStream_t stream) {
    const float* x     = (const float*)d_in[0];
    const float* ln_g  = (const float*)d_in[1];
    const float* uv_w  = (const float*)d_in[2];
    const float* uv_b  = (const float*)d_in[3];
    const float* gamma = (const float*)d_in[4];
    const float* beta  = (const float*)d_in[5];
    const float* wbias = (const float*)d_in[6];
    const float* o_w   = (const float*)d_in[7];
    const float* o_b   = (const float*)d_in[8];
    float* out = (float*)d_out;

    char* ws = (char*)d_ws;
    size_t off = 0;
    auto alloc = [&](size_t bytes) {
        void* p = ws + off;
        off += (bytes + 255) & ~(size_t)255;
        return p;
    };
    // Peak ~196.4 MiB:
    unsigned short* u     = (unsigned short*)alloc((size_t)M_TOT * E_DIMC * 2);      // 64 MiB (u, then oe in place)
    unsigned short* vT    = (unsigned short*)alloc((size_t)64 * E_DIMC * S_LEN * 2); // 64 MiB
    unsigned short* xn    = (unsigned short*)alloc((size_t)M_TOT * H_DIM * 2);       // 32 MiB
    unsigned short* P     = xn;                                                      // alias (xn dead after gemm1)
    float*          base  = (float*)alloc((size_t)M_TOT * D_DIM * 4);                // 16 MiB
    unsigned short* q     = (unsigned short*)alloc((size_t)M_TOT * D_DIM * 2);       // 8 MiB
    unsigned short* k     = (unsigned short*)alloc((size_t)M_TOT * D_DIM * 2);       // 8 MiB
    float*          cost  = (float*)alloc((size_t)S_LEN * 64 * 4);
    float*          sint  = (float*)alloc((size_t)S_LEN * 64 * 4);
    unsigned short* uvwb  = (unsigned short*)alloc((size_t)UV_DIM * H_DIM * 2);      // 2.2 MiB
    unsigned short* owb   = (unsigned short*)alloc((size_t)H_DIM * E_DIMC * 2);      // 1 MiB
    (void)ws_size; (void)in_sizes; (void)n_in; (void)out_size;

    f2bf_kernel<<<(UV_DIM * H_DIM / 4 + 255) / 256, 256, 0, stream>>>(uv_w, uvwb, UV_DIM * H_DIM / 4);
    f2bf_kernel<<<(H_DIM * E_DIMC / 4 + 255) / 256, 256, 0, stream>>>(o_w, owb, H_DIM * E_DIMC / 4);
    rope_table_kernel<<<S_LEN, 64, 0, stream>>>(cost, sint);

    rmsnorm_kernel<<<M_TOT / 4, 256, 0, stream>>>(x, ln_g, xn);

    // gemm1 + silu; writes u, vT (transposed), base
    gemm1_kernel<<<dim3(M_TOT / 128, UV_DIM / 128), 256, 0, stream>>>(xn, uvwb, uv_b, u, vT, base);

    rope_apply_kernel<<<M_TOT * 64 / 256, 256, 0, stream>>>(base, gamma, beta, cost, sint, q, k);

    // P = relu^2((q k^T + bias)/sqrt(128))   (overwrites xn region)
    gemm_qk_kernel<<<dim3(S_LEN / 128, S_LEN / 128, 64), 256, 0, stream>>>(q, k, wbias, P);

    // u <- u .* (P @ v)  in place
    gemm_pv_kernel<<<dim3(S_LEN / 128, E_DIMC / 128, 64), 256, 0, stream>>>(P, vT, u);

    // out = oe @ o_w^T + o_b + x
    gemm_out_kernel<<<dim3(M_TOT / 128, H_DIM / 128), 256, 0, stream>>>(u, owb, o_b, x, out);
}

// Round 3
// 428.064 us; speedup vs baseline: 1.0666x; 1.0666x over previous
//
#include <hip/hip_runtime.h>
#include <math.h>

// ---------------------------------------------------------------------------
// GAU-alpha fused block for MI355X (gfx950).
// B=64, S=512, H=512, E=1024, UV=2176, D=128, M=B*S=32768.
// bf16 MFMA (16x16x32) for all 4 matmuls, fp32 elsewhere.
// Round 3: GEMM staging via global_load_lds width=16 (m97 ladder step) with
// XOR-swizzled source columns so the unpadded LDS layout is bank-conflict-free
// on the ds_read_b128 fragment loads.
//   LDS[r][c] = G[r][c ^ 8*(r&7)]  (c in units of shorts, chunks of 8)
// ---------------------------------------------------------------------------

#define M_TOT   32768
#define S_LEN   512
#define H_DIM   512
#define E_DIMC  1024
#define UV_DIM  2176
#define D_DIM   128

using floatx4  = __attribute__((ext_vector_type(4))) float;
using uintx2   = __attribute__((ext_vector_type(2))) unsigned int;
using uintx4   = __attribute__((ext_vector_type(4))) unsigned int;
using ushortx4 = __attribute__((ext_vector_type(4))) unsigned short;
using short8   = __attribute__((ext_vector_type(8))) short;

#define ASYNC_CP16(gsrc, ldst)                                                  \
    __builtin_amdgcn_global_load_lds(                                           \
        (const __attribute__((address_space(1))) void*)(gsrc),                  \
        (__attribute__((address_space(3))) void*)(ldst), 16, 0, 0)

__device__ __forceinline__ float bf2f(unsigned short h) {
    union { unsigned int u; float f; } c;
    c.u = ((unsigned int)h) << 16;
    return c.f;
}
__device__ __forceinline__ unsigned short f2bf(float f) {
    union { float f; unsigned int u; } c;
    c.f = f;
    unsigned int r = c.u + 0x7fffu + ((c.u >> 16) & 1u);  // RNE
    return (unsigned short)(r >> 16);
}

// ---------------------------------------------------------------------------
__global__ __launch_bounds__(256) void f2bf_kernel(const float* __restrict__ in,
                                                   unsigned short* __restrict__ out,
                                                   int n4) {
    int i = blockIdx.x * 256 + threadIdx.x;
    if (i < n4) {
        floatx4 v = ((const floatx4*)in)[i];
        ushortx4 o;
        o.x = f2bf(v.x); o.y = f2bf(v.y); o.z = f2bf(v.z); o.w = f2bf(v.w);
        ((ushortx4*)out)[i] = o;
    }
}

// ---------------------------------------------------------------------------
__global__ __launch_bounds__(256) void rmsnorm_kernel(const float* __restrict__ x,
                                                      const float* __restrict__ ln_g,
                                                      unsigned short* __restrict__ xn) {
    int row  = blockIdx.x * 4 + (threadIdx.x >> 6);
    int lane = threadIdx.x & 63;
    const float* xr = x + (size_t)row * H_DIM;
    floatx4 v0 = ((const floatx4*)xr)[lane];
    floatx4 v1 = ((const floatx4*)xr)[lane + 64];
    float ss = v0.x*v0.x + v0.y*v0.y + v0.z*v0.z + v0.w*v0.w
             + v1.x*v1.x + v1.y*v1.y + v1.z*v1.z + v1.w*v1.w;
    #pragma unroll
    for (int off = 32; off > 0; off >>= 1) ss += __shfl_xor(ss, off, 64);
    float norm = sqrtf(ss) * 0.044194173824159216f;  // * H^-0.5
    float sc   = ln_g[0] / fmaxf(norm, 1e-5f);
    unsigned short* xo = xn + (size_t)row * H_DIM;
    ushortx4 o0, o1;
    o0.x = f2bf(v0.x * sc); o0.y = f2bf(v0.y * sc);
    o0.z = f2bf(v0.z * sc); o0.w = f2bf(v0.w * sc);
    o1.x = f2bf(v1.x * sc); o1.y = f2bf(v1.y * sc);
    o1.z = f2bf(v1.z * sc); o1.w = f2bf(v1.w * sc);
    ((ushortx4*)xo)[lane]      = o0;
    ((ushortx4*)xo)[lane + 64] = o1;
}

// ---------------------------------------------------------------------------
// RoPE tables — mimic fp32 numpy: inv_freq = fp32-rounded, angle = fp32
// product, sin/cos correctly rounded of that exact fp32 argument.
// ---------------------------------------------------------------------------
__global__ __launch_bounds__(64) void rope_table_kernel(float* __restrict__ cost,
                                                        float* __restrict__ sint) {
    int s = blockIdx.x;
    int j = threadIdx.x;  // 0..63
    float invf = (float)pow(10000.0, (double)j / 64.0);
    float ang  = (float)s * invf;  // fp32 multiply like the f32 reference
    double a   = (double)ang;
    cost[s * 64 + j] = (float)cos(a);
    sint[s * 64 + j] = (float)sin(a);
}

// ---------------------------------------------------------------------------
__global__ __launch_bounds__(256) void rope_apply_kernel(const float* __restrict__ base,
                                                         const float* __restrict__ gamma,
                                                         const float* __restrict__ beta,
                                                         const float* __restrict__ cost,
                                                         const float* __restrict__ sint,
                                                         unsigned short* __restrict__ q,
                                                         unsigned short* __restrict__ k) {
    int idx = blockIdx.x * 256 + threadIdx.x;  // M*64 total
    int m = idx >> 6;
    int j = idx & 63;
    int s = m & (S_LEN - 1);
    float b1 = base[(size_t)m * D_DIM + j];
    float b2 = base[(size_t)m * D_DIM + 64 + j];
    float c  = cost[s * 64 + j];
    float sn = sint[s * 64 + j];
    float yq1 = b1 * gamma[j]       + beta[j];
    float yq2 = b2 * gamma[64 + j]  + beta[64 + j];
    float yk1 = b1 * gamma[128 + j] + beta[128 + j];
    float yk2 = b2 * gamma[192 + j] + beta[192 + j];
    q[(size_t)m * D_DIM + j]      = f2bf(yq1 * c - yq2 * sn);
    q[(size_t)m * D_DIM + 64 + j] = f2bf(yq2 * c + yq1 * sn);
    k[(size_t)m * D_DIM + j]      = f2bf(yk1 * c - yk2 * sn);
    k[(size_t)m * D_DIM + 64 + j] = f2bf(yk2 * c + yk1 * sn);
}

// ---------------------------------------------------------------------------
// GEMM core, B^T form: C[m][n] = sum_k A[m][k]*B[n][k], A/B bf16 row-major.
// 128x128 tile, 256 threads (4 waves, 2x2 of 64x64), 16x16x32 bf16 MFMA,
// BK=64. Staging: global_load_lds width=16, wave w stages rows [w*32,w*32+32)
// in 4 issues of 8 rows; lane l covers row lrow=l>>3, chunk (l&7), and loads
// global chunk (l&7)^lrow so LDS holds the XOR-swizzled layout.
// Fragment layouts (HW-verified per guide):
//   A: A[m = lane&15][k = (lane>>4)*8 + j]
//   B: B-row n = lane&15, k = (lane>>4)*8 + j
//   C: col = lane&15, row = (lane>>4)*4 + reg
// ---------------------------------------------------------------------------
struct GemmLds {
    unsigned short As[128 * 64];
    unsigned short Bs[128 * 64];
};

__device__ __forceinline__ void gemm_bt_core(const unsigned short* __restrict__ A,
                                             const unsigned short* __restrict__ B,
                                             int lda, int ldb, int K,
                                             int m0, int n0,
                                             GemmLds& lds, floatx4 (&acc)[4][4]) {
    const int tid  = threadIdx.x;
    const int lane = tid & 63;
    const int wave = tid >> 6;
    const int quad = lane >> 4;
    const int l16  = lane & 15;
    const int wm   = (wave >> 1) * 64;
    const int wn   = (wave & 1) * 64;
    const int lrow = lane >> 3;                    // 0..7 (also row&7 of my row)
    const int cgs  = ((lane & 7) ^ lrow) * 8;      // swizzled source col (shorts)

    #pragma unroll
    for (int i = 0; i < 4; i++)
        #pragma unroll
        for (int j = 0; j < 4; j++) acc[i][j] = (floatx4){0.f, 0.f, 0.f, 0.f};

    for (int kt = 0; kt < K; kt += 64) {
        #pragma unroll
        for (int i = 0; i < 4; i++) {
            int r0 = wave * 32 + i * 8;
            const unsigned short* ga = A + (size_t)(m0 + r0 + lrow) * lda + kt + cgs;
            const unsigned short* gb = B + (size_t)(n0 + r0 + lrow) * ldb + kt + cgs;
            ASYNC_CP16(ga, &lds.As[r0 * 64]);
            ASYNC_CP16(gb, &lds.Bs[r0 * 64]);
        }
        __syncthreads();   // drains vmcnt before barrier (compiler-inserted)
        #pragma unroll
        for (int kk = 0; kk < 64; kk += 32) {
            short8 af[4], bf[4];
            const int pc = (kk + quad * 8) ^ ((l16 & 7) * 8);  // physical col
            #pragma unroll
            for (int mt = 0; mt < 4; mt++) {
                int row = wm + mt * 16 + l16;
                union { short8 s8; uintx4 u4; } fu;
                fu.u4 = *(const uintx4*)&lds.As[row * 64 + pc];
                af[mt] = fu.s8;
            }
            #pragma unroll
            for (int nt = 0; nt < 4; nt++) {
                int row = wn + nt * 16 + l16;
                union { short8 s8; uintx4 u4; } fu;
                fu.u4 = *(const uintx4*)&lds.Bs[row * 64 + pc];
                bf[nt] = fu.s8;
            }
            #pragma unroll
            for (int mt = 0; mt < 4; mt++)
                #pragma unroll
                for (int nt = 0; nt < 4; nt++)
                    acc[mt][nt] = __builtin_amdgcn_mfma_f32_16x16x32_bf16(
                        af[mt], bf[nt], acc[mt][nt], 0, 0, 0);
        }
        __syncthreads();
    }
}

// ---------------------------------------------------------------------------
// GEMM1: act = silu(xn @ uv_w^T + uv_b).
//   blockIdx.y <  8 : u columns, write u (m,e) bf16
//   blockIdx.y 8..15: v columns, LDS-transpose tile, write vT (b,e,s) bf16
//   blockIdx.y == 16: base columns, write fp32
// ---------------------------------------------------------------------------
__global__ __launch_bounds__(256) void gemm1_kernel(const unsigned short* __restrict__ xn,
                                                    const unsigned short* __restrict__ uvw,
                                                    const float* __restrict__ uvb,
                                                    unsigned short* __restrict__ u,
                                                    unsigned short* __restrict__ vT,
                                                    float* __restrict__ base) {
    __shared__ union LdsU {
        GemmLds g;
        unsigned short T[128 * 136];   // 34816 B
    } lds;
    floatx4 acc[4][4];
    const int m0 = blockIdx.x * 128, n0 = blockIdx.y * 128;
    gemm_bt_core(xn, uvw, H_DIM, H_DIM, H_DIM, m0, n0, lds.g, acc);

    const int tid  = threadIdx.x;
    const int lane = tid & 63;
    const int wave = tid >> 6;
    const int quad = lane >> 4;
    const int l16  = lane & 15;
    const int wm   = (wave >> 1) * 64;
    const int wn   = (wave & 1) * 64;

    if (blockIdx.y < 8) {
        #pragma unroll
        for (int mt = 0; mt < 4; mt++)
            #pragma unroll
            for (int nt = 0; nt < 4; nt++)
                #pragma unroll
                for (int r = 0; r < 4; r++) {
                    int m = m0 + wm + mt * 16 + quad * 4 + r;
                    int n = n0 + wn + nt * 16 + l16;
                    float val = acc[mt][nt][r] + uvb[n];
                    u[(size_t)m * E_DIMC + n] = f2bf(val / (1.0f + expf(-val)));
                }
    } else if (blockIdx.y == 16) {
        #pragma unroll
        for (int mt = 0; mt < 4; mt++)
            #pragma unroll
            for (int nt = 0; nt < 4; nt++)
                #pragma unroll
                for (int r = 0; r < 4; r++) {
                    int m = m0 + wm + mt * 16 + quad * 4 + r;
                    int n = n0 + wn + nt * 16 + l16;
                    float val = acc[mt][nt][r] + uvb[n];
                    base[(size_t)m * D_DIM + (n - 2 * E_DIMC)] = val / (1.0f + expf(-val));
                }
    } else {
        // v tile: transpose through LDS (core's trailing __syncthreads makes
        // reuse safe), then coalesced store to vT (b, e, s).
        #pragma unroll
        for (int mt = 0; mt < 4; mt++)
            #pragma unroll
            for (int nt = 0; nt < 4; nt++)
                #pragma unroll
                for (int r = 0; r < 4; r++) {
                    int ml = wm + mt * 16 + quad * 4 + r;     // local m (s)
                    int nl = wn + nt * 16 + l16;              // local n (e)
                    float val = acc[mt][nt][r] + uvb[n0 + nl];
                    lds.T[nl * 136 + ml] = f2bf(val / (1.0f + expf(-val)));
                }
        __syncthreads();
        const int b   = m0 >> 9;           // 128-row tile lies in one batch
        const int sg0 = m0 & (S_LEN - 1);
        const int eg0 = n0 - E_DIMC;       // n0 in [1024,2048)
        #pragma unroll
        for (int i = 0; i < 8; i++) {
            int idx = tid + i * 256;       // 0..2047
            int e   = idx >> 4;            // 0..127
            int s8  = (idx & 15) * 8;      // 0..120
            uintx4 val = *(const uintx4*)&lds.T[e * 136 + s8];
            *(uintx4*)(vT + ((size_t)b * E_DIMC + eg0 + e) * S_LEN + sg0 + s8) = val;
        }
    }
}

// ---------------------------------------------------------------------------
// qk GEMM (batched over b): P = relu((q k^T + w_bias)/sqrt(128))^2, bf16
// ---------------------------------------------------------------------------
__global__ __launch_bounds__(256) void gemm_qk_kernel(const unsigned short* __restrict__ q,
                                                      const unsigned short* __restrict__ k,
                                                      const float* __restrict__ wbias,
                                                      unsigned short* __restrict__ P) {
    __shared__ GemmLds lds;
    floatx4 acc[4][4];
    size_t boff = (size_t)blockIdx.z * S_LEN * D_DIM;
    unsigned short* Pb = P + (size_t)blockIdx.z * S_LEN * S_LEN;
    const int m0 = blockIdx.x * 128, n0 = blockIdx.y * 128;
    gemm_bt_core(q + boff, k + boff, D_DIM, D_DIM, D_DIM, m0, n0, lds, acc);

    const int tid = threadIdx.x, lane = tid & 63, wave = tid >> 6;
    const int quad = lane >> 4, l16 = lane & 15;
    const int wm = (wave >> 1) * 64, wn = (wave & 1) * 64;
    #pragma unroll
    for (int mt = 0; mt < 4; mt++)
        #pragma unroll
        for (int nt = 0; nt < 4; nt++)
            #pragma unroll
            for (int r = 0; r < 4; r++) {
                int s = m0 + wm + mt * 16 + quad * 4 + r;
                int t = n0 + wn + nt * 16 + l16;
                float z = (acc[mt][nt][r] + wbias[t - s + (S_LEN - 1)]) * 0.08838834764831845f;
                z = fmaxf(z, 0.f);
                Pb[(size_t)s * S_LEN + t] = f2bf(z * z);
            }
}

// ---------------------------------------------------------------------------
// PV GEMM (batched): u <- u .* (P @ v)  [in place; each element touched once]
// ---------------------------------------------------------------------------
__global__ __launch_bounds__(256) void gemm_pv_kernel(const unsigned short* __restrict__ P,
                                                      const unsigned short* __restrict__ vT,
                                                      unsigned short* __restrict__ u) {
    __shared__ GemmLds lds;
    floatx4 acc[4][4];
    int bb = blockIdx.z;
    const unsigned short* Pb  = P  + (size_t)bb * S_LEN * S_LEN;
    const unsigned short* vTb = vT + (size_t)bb * E_DIMC * S_LEN;
    const int m0 = blockIdx.x * 128, n0 = blockIdx.y * 128;
    gemm_bt_core(Pb, vTb, S_LEN, S_LEN, S_LEN, m0, n0, lds, acc);

    const int tid = threadIdx.x, lane = tid & 63, wave = tid >> 6;
    const int quad = lane >> 4, l16 = lane & 15;
    const int wm = (wave >> 1) * 64, wn = (wave & 1) * 64;
    #pragma unroll
    for (int mt = 0; mt < 4; mt++)
        #pragma unroll
        for (int nt = 0; nt < 4; nt++)
            #pragma unroll
            for (int r = 0; r < 4; r++) {
                int s = m0 + wm + mt * 16 + quad * 4 + r;
                int e = n0 + wn + nt * 16 + l16;
                size_t off = ((size_t)bb * S_LEN + s) * E_DIMC + e;
                u[off] = f2bf(acc[mt][nt][r] * bf2f(u[off]));
            }
}

// ---------------------------------------------------------------------------
// Output GEMM: out = oe @ o_w^T + o_b + x   (fp32 out; oe aliases u)
// ---------------------------------------------------------------------------
__global__ __launch_bounds__(256) void gemm_out_kernel(const unsigned short* __restrict__ oe,
                                                       const unsigned short* __restrict__ ow,
                                                       const float* __restrict__ ob,
                                                       const float* __restrict__ x,
                                                       float* __restrict__ out) {
    __shared__ GemmLds lds;
    floatx4 acc[4][4];
    const int m0 = blockIdx.x * 128, n0 = blockIdx.y * 128;
    gemm_bt_core(oe, ow, E_DIMC, E_DIMC, E_DIMC, m0, n0, lds, acc);

    const int tid = threadIdx.x, lane = tid & 63, wave = tid >> 6;
    const int quad = lane >> 4, l16 = lane & 15;
    const int wm = (wave >> 1) * 64, wn = (wave & 1) * 64;
    #pragma unroll
    for (int mt = 0; mt < 4; mt++)
        #pragma unroll
        for (int nt = 0; nt < 4; nt++)
            #pragma unroll
            for (int r = 0; r < 4; r++) {
                int m = m0 + wm + mt * 16 + quad * 4 + r;
                int n = n0 + wn + nt * 16 + l16;
                size_t off = (size_t)m * H_DIM + n;
                out[off] = acc[mt][nt][r] + ob[n] + x[off];
            }
}

// ---------------------------------------------------------------------------
extern "C" void kernel_launch(void* const* d_in, const int* in_sizes, int n_in,
                              void* d_out, int out_size, void* d_ws, size_t ws_size,
                              hipStream_t stream) {
    const float* x     = (const float*)d_in[0];
    const float* ln_g  = (const float*)d_in[1];
    const float* uv_w  = (const float*)d_in[2];
    const float* uv_b  = (const float*)d_in[3];
    const float* gamma = (const float*)d_in[4];
    const float* beta  = (const float*)d_in[5];
    const float* wbias = (const float*)d_in[6];
    const float* o_w   = (const float*)d_in[7];
    const float* o_b   = (const float*)d_in[8];
    float* out = (float*)d_out;

    char* ws = (char*)d_ws;
    size_t off = 0;
    auto alloc = [&](size_t bytes) {
        void* p = ws + off;
        off += (bytes + 255) & ~(size_t)255;
        return p;
    };
    // Peak ~196.4 MiB:
    unsigned short* u     = (unsigned short*)alloc((size_t)M_TOT * E_DIMC * 2);      // 64 MiB (u, then oe in place)
    unsigned short* vT    = (unsigned short*)alloc((size_t)64 * E_DIMC * S_LEN * 2); // 64 MiB
    unsigned short* xn    = (unsigned short*)alloc((size_t)M_TOT * H_DIM * 2);       // 32 MiB
    unsigned short* P     = xn;                                                      // alias (xn dead after gemm1)
    float*          base  = (float*)alloc((size_t)M_TOT * D_DIM * 4);                // 16 MiB
    unsigned short* q     = (unsigned short*)alloc((size_t)M_TOT * D_DIM * 2);       // 8 MiB
    unsigned short* k     = (unsigned short*)alloc((size_t)M_TOT * D_DIM * 2);       // 8 MiB
    float*          cost  = (float*)alloc((size_t)S_LEN * 64 * 4);
    float*          sint  = (float*)alloc((size_t)S_LEN * 64 * 4);
    unsigned short* uvwb  = (unsigned short*)alloc((size_t)UV_DIM * H_DIM * 2);      // 2.2 MiB
    unsigned short* owb   = (unsigned short*)alloc((size_t)H_DIM * E_DIMC * 2);      // 1 MiB
    (void)ws_size; (void)in_sizes; (void)n_in; (void)out_size;

    f2bf_kernel<<<(UV_DIM * H_DIM / 4 + 255) / 256, 256, 0, stream>>>(uv_w, uvwb, UV_DIM * H_DIM / 4);
    f2bf_kernel<<<(H_DIM * E_DIMC / 4 + 255) / 256, 256, 0, stream>>>(o_w, owb, H_DIM * E_DIMC / 4);
    rope_table_kernel<<<S_LEN, 64, 0, stream>>>(cost, sint);

    rmsnorm_kernel<<<M_TOT / 4, 256, 0, stream>>>(x, ln_g, xn);

    // gemm1 + silu; writes u, vT (transposed), base
    gemm1_kernel<<<dim3(M_TOT / 128, UV_DIM / 128), 256, 0, stream>>>(xn, uvwb, uv_b, u, vT, base);

    rope_apply_kernel<<<M_TOT * 64 / 256, 256, 0, stream>>>(base, gamma, beta, cost, sint, q, k);

    // P = relu^2((q k^T + bias)/sqrt(128))   (overwrites xn region)
    gemm_qk_kernel<<<dim3(S_LEN / 128, S_LEN / 128, 64), 256, 0, stream>>>(q, k, wbias, P);

    // u <- u .* (P @ v)  in place
    gemm_pv_kernel<<<dim3(S_LEN / 128, E_DIMC / 128, 64), 256, 0, stream>>>(P, vT, u);

    // out = oe @ o_w^T + o_b + x
    gemm_out_kernel<<<dim3(M_TOT / 128, H_DIM / 128), 256, 0, stream>>>(u, owb, o_b, x, out);
}

// Round 4
// 401.214 us; speedup vs baseline: 1.1380x; 1.0669x over previous
//
#include <hip/hip_runtime.h>
#include <math.h>

// ---------------------------------------------------------------------------
// GAU-alpha fused block for MI355X (gfx950).
// B=64, S=512, H=512, E=1024, UV=2176, D=128, M=B*S=32768.
// bf16 MFMA (16x16x32) for all 4 matmuls, fp32 elsewhere.
// Round 4: silu via v_exp_f32 + v_rcp_f32 (round-3 post-mortem: gemm1 was
// epilogue-bound on libm expf — 71M calls ~= 2.6x the K-loop MFMA cycles).
// ---------------------------------------------------------------------------

#define M_TOT   32768
#define S_LEN   512
#define H_DIM   512
#define E_DIMC  1024
#define UV_DIM  2176
#define D_DIM   128

using floatx4  = __attribute__((ext_vector_type(4))) float;
using uintx2   = __attribute__((ext_vector_type(2))) unsigned int;
using uintx4   = __attribute__((ext_vector_type(4))) unsigned int;
using ushortx4 = __attribute__((ext_vector_type(4))) unsigned short;
using short8   = __attribute__((ext_vector_type(8))) short;

#define ASYNC_CP16(gsrc, ldst)                                                  \
    __builtin_amdgcn_global_load_lds(                                           \
        (const __attribute__((address_space(1))) void*)(gsrc),                  \
        (__attribute__((address_space(3))) void*)(ldst), 16, 0, 0)

__device__ __forceinline__ float bf2f(unsigned short h) {
    union { unsigned int u; float f; } c;
    c.u = ((unsigned int)h) << 16;
    return c.f;
}
__device__ __forceinline__ unsigned short f2bf(float f) {
    union { float f; unsigned int u; } c;
    c.f = f;
    unsigned int r = c.u + 0x7fffu + ((c.u >> 16) & 1u);  // RNE
    return (unsigned short)(r >> 16);
}
// silu via HW transcendentals: v_exp_f32 + v_rcp_f32 (~1 ulp each; invisible
// under bf16 output rounding).
__device__ __forceinline__ float silu_fast(float x) {
    float e = __expf(-x);                       // v_exp_f32 path
    return x * __builtin_amdgcn_rcpf(1.0f + e); // v_rcp_f32
}

// ---------------------------------------------------------------------------
__global__ __launch_bounds__(256) void f2bf_kernel(const float* __restrict__ in,
                                                   unsigned short* __restrict__ out,
                                                   int n4) {
    int i = blockIdx.x * 256 + threadIdx.x;
    if (i < n4) {
        floatx4 v = ((const floatx4*)in)[i];
        ushortx4 o;
        o.x = f2bf(v.x); o.y = f2bf(v.y); o.z = f2bf(v.z); o.w = f2bf(v.w);
        ((ushortx4*)out)[i] = o;
    }
}

// ---------------------------------------------------------------------------
__global__ __launch_bounds__(256) void rmsnorm_kernel(const float* __restrict__ x,
                                                      const float* __restrict__ ln_g,
                                                      unsigned short* __restrict__ xn) {
    int row  = blockIdx.x * 4 + (threadIdx.x >> 6);
    int lane = threadIdx.x & 63;
    const float* xr = x + (size_t)row * H_DIM;
    floatx4 v0 = ((const floatx4*)xr)[lane];
    floatx4 v1 = ((const floatx4*)xr)[lane + 64];
    float ss = v0.x*v0.x + v0.y*v0.y + v0.z*v0.z + v0.w*v0.w
             + v1.x*v1.x + v1.y*v1.y + v1.z*v1.z + v1.w*v1.w;
    #pragma unroll
    for (int off = 32; off > 0; off >>= 1) ss += __shfl_xor(ss, off, 64);
    float norm = sqrtf(ss) * 0.044194173824159216f;  // * H^-0.5
    float sc   = ln_g[0] / fmaxf(norm, 1e-5f);
    unsigned short* xo = xn + (size_t)row * H_DIM;
    ushortx4 o0, o1;
    o0.x = f2bf(v0.x * sc); o0.y = f2bf(v0.y * sc);
    o0.z = f2bf(v0.z * sc); o0.w = f2bf(v0.w * sc);
    o1.x = f2bf(v1.x * sc); o1.y = f2bf(v1.y * sc);
    o1.z = f2bf(v1.z * sc); o1.w = f2bf(v1.w * sc);
    ((ushortx4*)xo)[lane]      = o0;
    ((ushortx4*)xo)[lane + 64] = o1;
}

// ---------------------------------------------------------------------------
// RoPE tables — mimic fp32 numpy: inv_freq = fp32-rounded, angle = fp32
// product, sin/cos correctly rounded of that exact fp32 argument.
// ---------------------------------------------------------------------------
__global__ __launch_bounds__(64) void rope_table_kernel(float* __restrict__ cost,
                                                        float* __restrict__ sint) {
    int s = blockIdx.x;
    int j = threadIdx.x;  // 0..63
    float invf = (float)pow(10000.0, (double)j / 64.0);
    float ang  = (float)s * invf;  // fp32 multiply like the f32 reference
    double a   = (double)ang;
    cost[s * 64 + j] = (float)cos(a);
    sint[s * 64 + j] = (float)sin(a);
}

// ---------------------------------------------------------------------------
__global__ __launch_bounds__(256) void rope_apply_kernel(const float* __restrict__ base,
                                                         const float* __restrict__ gamma,
                                                         const float* __restrict__ beta,
                                                         const float* __restrict__ cost,
                                                         const float* __restrict__ sint,
                                                         unsigned short* __restrict__ q,
                                                         unsigned short* __restrict__ k) {
    int idx = blockIdx.x * 256 + threadIdx.x;  // M*64 total
    int m = idx >> 6;
    int j = idx & 63;
    int s = m & (S_LEN - 1);
    float b1 = base[(size_t)m * D_DIM + j];
    float b2 = base[(size_t)m * D_DIM + 64 + j];
    float c  = cost[s * 64 + j];
    float sn = sint[s * 64 + j];
    float yq1 = b1 * gamma[j]       + beta[j];
    float yq2 = b2 * gamma[64 + j]  + beta[64 + j];
    float yk1 = b1 * gamma[128 + j] + beta[128 + j];
    float yk2 = b2 * gamma[192 + j] + beta[192 + j];
    q[(size_t)m * D_DIM + j]      = f2bf(yq1 * c - yq2 * sn);
    q[(size_t)m * D_DIM + 64 + j] = f2bf(yq2 * c + yq1 * sn);
    k[(size_t)m * D_DIM + j]      = f2bf(yk1 * c - yk2 * sn);
    k[(size_t)m * D_DIM + 64 + j] = f2bf(yk2 * c + yk1 * sn);
}

// ---------------------------------------------------------------------------
// GEMM core, B^T form: C[m][n] = sum_k A[m][k]*B[n][k], A/B bf16 row-major.
// 128x128 tile, 256 threads (4 waves, 2x2 of 64x64), 16x16x32 bf16 MFMA,
// BK=64. Staging: global_load_lds width=16, XOR-swizzled source columns:
//   LDS[r][c] = G[r][c ^ 8*(r&7)]  -> conflict-free ds_read_b128 fragments.
// Fragment layouts (HW-verified per guide):
//   A: A[m = lane&15][k = (lane>>4)*8 + j]
//   B: B-row n = lane&15, k = (lane>>4)*8 + j
//   C: col = lane&15, row = (lane>>4)*4 + reg
// ---------------------------------------------------------------------------
struct GemmLds {
    unsigned short As[128 * 64];
    unsigned short Bs[128 * 64];
};

__device__ __forceinline__ void gemm_bt_core(const unsigned short* __restrict__ A,
                                             const unsigned short* __restrict__ B,
                                             int lda, int ldb, int K,
                                             int m0, int n0,
                                             GemmLds& lds, floatx4 (&acc)[4][4]) {
    const int tid  = threadIdx.x;
    const int lane = tid & 63;
    const int wave = tid >> 6;
    const int quad = lane >> 4;
    const int l16  = lane & 15;
    const int wm   = (wave >> 1) * 64;
    const int wn   = (wave & 1) * 64;
    const int lrow = lane >> 3;                    // 0..7 (also row&7 of my row)
    const int cgs  = ((lane & 7) ^ lrow) * 8;      // swizzled source col (shorts)

    #pragma unroll
    for (int i = 0; i < 4; i++)
        #pragma unroll
        for (int j = 0; j < 4; j++) acc[i][j] = (floatx4){0.f, 0.f, 0.f, 0.f};

    for (int kt = 0; kt < K; kt += 64) {
        #pragma unroll
        for (int i = 0; i < 4; i++) {
            int r0 = wave * 32 + i * 8;
            const unsigned short* ga = A + (size_t)(m0 + r0 + lrow) * lda + kt + cgs;
            const unsigned short* gb = B + (size_t)(n0 + r0 + lrow) * ldb + kt + cgs;
            ASYNC_CP16(ga, &lds.As[r0 * 64]);
            ASYNC_CP16(gb, &lds.Bs[r0 * 64]);
        }
        __syncthreads();   // drains vmcnt before barrier (compiler-inserted)
        #pragma unroll
        for (int kk = 0; kk < 64; kk += 32) {
            short8 af[4], bf[4];
            const int pc = (kk + quad * 8) ^ ((l16 & 7) * 8);  // physical col
            #pragma unroll
            for (int mt = 0; mt < 4; mt++) {
                int row = wm + mt * 16 + l16;
                union { short8 s8; uintx4 u4; } fu;
                fu.u4 = *(const uintx4*)&lds.As[row * 64 + pc];
                af[mt] = fu.s8;
            }
            #pragma unroll
            for (int nt = 0; nt < 4; nt++) {
                int row = wn + nt * 16 + l16;
                union { short8 s8; uintx4 u4; } fu;
                fu.u4 = *(const uintx4*)&lds.Bs[row * 64 + pc];
                bf[nt] = fu.s8;
            }
            #pragma unroll
            for (int mt = 0; mt < 4; mt++)
                #pragma unroll
                for (int nt = 0; nt < 4; nt++)
                    acc[mt][nt] = __builtin_amdgcn_mfma_f32_16x16x32_bf16(
                        af[mt], bf[nt], acc[mt][nt], 0, 0, 0);
        }
        __syncthreads();
    }
}

// ---------------------------------------------------------------------------
// GEMM1: act = silu(xn @ uv_w^T + uv_b).
//   blockIdx.y <  8 : u columns, write u (m,e) bf16
//   blockIdx.y 8..15: v columns, LDS-transpose tile, write vT (b,e,s) bf16
//   blockIdx.y == 16: base columns, write fp32
// ---------------------------------------------------------------------------
__global__ __launch_bounds__(256) void gemm1_kernel(const unsigned short* __restrict__ xn,
                                                    const unsigned short* __restrict__ uvw,
                                                    const float* __restrict__ uvb,
                                                    unsigned short* __restrict__ u,
                                                    unsigned short* __restrict__ vT,
                                                    float* __restrict__ base) {
    __shared__ union LdsU {
        GemmLds g;
        unsigned short T[128 * 136];   // 34816 B
    } lds;
    floatx4 acc[4][4];
    const int m0 = blockIdx.x * 128, n0 = blockIdx.y * 128;
    gemm_bt_core(xn, uvw, H_DIM, H_DIM, H_DIM, m0, n0, lds.g, acc);

    const int tid  = threadIdx.x;
    const int lane = tid & 63;
    const int wave = tid >> 6;
    const int quad = lane >> 4;
    const int l16  = lane & 15;
    const int wm   = (wave >> 1) * 64;
    const int wn   = (wave & 1) * 64;

    if (blockIdx.y < 8) {
        #pragma unroll
        for (int mt = 0; mt < 4; mt++)
            #pragma unroll
            for (int nt = 0; nt < 4; nt++)
                #pragma unroll
                for (int r = 0; r < 4; r++) {
                    int m = m0 + wm + mt * 16 + quad * 4 + r;
                    int n = n0 + wn + nt * 16 + l16;
                    float val = acc[mt][nt][r] + uvb[n];
                    u[(size_t)m * E_DIMC + n] = f2bf(silu_fast(val));
                }
    } else if (blockIdx.y == 16) {
        #pragma unroll
        for (int mt = 0; mt < 4; mt++)
            #pragma unroll
            for (int nt = 0; nt < 4; nt++)
                #pragma unroll
                for (int r = 0; r < 4; r++) {
                    int m = m0 + wm + mt * 16 + quad * 4 + r;
                    int n = n0 + wn + nt * 16 + l16;
                    float val = acc[mt][nt][r] + uvb[n];
                    base[(size_t)m * D_DIM + (n - 2 * E_DIMC)] = silu_fast(val);
                }
    } else {
        // v tile: transpose through LDS (core's trailing __syncthreads makes
        // reuse safe), then coalesced store to vT (b, e, s).
        #pragma unroll
        for (int mt = 0; mt < 4; mt++)
            #pragma unroll
            for (int nt = 0; nt < 4; nt++)
                #pragma unroll
                for (int r = 0; r < 4; r++) {
                    int ml = wm + mt * 16 + quad * 4 + r;     // local m (s)
                    int nl = wn + nt * 16 + l16;              // local n (e)
                    float val = acc[mt][nt][r] + uvb[n0 + nl];
                    lds.T[nl * 136 + ml] = f2bf(silu_fast(val));
                }
        __syncthreads();
        const int b   = m0 >> 9;           // 128-row tile lies in one batch
        const int sg0 = m0 & (S_LEN - 1);
        const int eg0 = n0 - E_DIMC;       // n0 in [1024,2048)
        #pragma unroll
        for (int i = 0; i < 8; i++) {
            int idx = tid + i * 256;       // 0..2047
            int e   = idx >> 4;            // 0..127
            int s8  = (idx & 15) * 8;      // 0..120
            uintx4 val = *(const uintx4*)&lds.T[e * 136 + s8];
            *(uintx4*)(vT + ((size_t)b * E_DIMC + eg0 + e) * S_LEN + sg0 + s8) = val;
        }
    }
}

// ---------------------------------------------------------------------------
// qk GEMM (batched over b): P = relu((q k^T + w_bias)/sqrt(128))^2, bf16
// ---------------------------------------------------------------------------
__global__ __launch_bounds__(256) void gemm_qk_kernel(const unsigned short* __restrict__ q,
                                                      const unsigned short* __restrict__ k,
                                                      const float* __restrict__ wbias,
                                                      unsigned short* __restrict__ P) {
    __shared__ GemmLds lds;
    floatx4 acc[4][4];
    size_t boff = (size_t)blockIdx.z * S_LEN * D_DIM;
    unsigned short* Pb = P + (size_t)blockIdx.z * S_LEN * S_LEN;
    const int m0 = blockIdx.x * 128, n0 = blockIdx.y * 128;
    gemm_bt_core(q + boff, k + boff, D_DIM, D_DIM, D_DIM, m0, n0, lds, acc);

    const int tid = threadIdx.x, lane = tid & 63, wave = tid >> 6;
    const int quad = lane >> 4, l16 = lane & 15;
    const int wm = (wave >> 1) * 64, wn = (wave & 1) * 64;
    #pragma unroll
    for (int mt = 0; mt < 4; mt++)
        #pragma unroll
        for (int nt = 0; nt < 4; nt++)
            #pragma unroll
            for (int r = 0; r < 4; r++) {
                int s = m0 + wm + mt * 16 + quad * 4 + r;
                int t = n0 + wn + nt * 16 + l16;
                float z = (acc[mt][nt][r] + wbias[t - s + (S_LEN - 1)]) * 0.08838834764831845f;
                z = fmaxf(z, 0.f);
                Pb[(size_t)s * S_LEN + t] = f2bf(z * z);
            }
}

// ---------------------------------------------------------------------------
// PV GEMM (batched): u <- u .* (P @ v)  [in place; each element touched once]
// ---------------------------------------------------------------------------
__global__ __launch_bounds__(256) void gemm_pv_kernel(const unsigned short* __restrict__ P,
                                                      const unsigned short* __restrict__ vT,
                                                      unsigned short* __restrict__ u) {
    __shared__ GemmLds lds;
    floatx4 acc[4][4];
    int bb = blockIdx.z;
    const unsigned short* Pb  = P  + (size_t)bb * S_LEN * S_LEN;
    const unsigned short* vTb = vT + (size_t)bb * E_DIMC * S_LEN;
    const int m0 = blockIdx.x * 128, n0 = blockIdx.y * 128;
    gemm_bt_core(Pb, vTb, S_LEN, S_LEN, S_LEN, m0, n0, lds, acc);

    const int tid = threadIdx.x, lane = tid & 63, wave = tid >> 6;
    const int quad = lane >> 4, l16 = lane & 15;
    const int wm = (wave >> 1) * 64, wn = (wave & 1) * 64;
    #pragma unroll
    for (int mt = 0; mt < 4; mt++)
        #pragma unroll
        for (int nt = 0; nt < 4; nt++)
            #pragma unroll
            for (int r = 0; r < 4; r++) {
                int s = m0 + wm + mt * 16 + quad * 4 + r;
                int e = n0 + wn + nt * 16 + l16;
                size_t off = ((size_t)bb * S_LEN + s) * E_DIMC + e;
                u[off] = f2bf(acc[mt][nt][r] * bf2f(u[off]));
            }
}

// ---------------------------------------------------------------------------
// Output GEMM: out = oe @ o_w^T + o_b + x   (fp32 out; oe aliases u)
// ---------------------------------------------------------------------------
__global__ __launch_bounds__(256) void gemm_out_kernel(const unsigned short* __restrict__ oe,
                                                       const unsigned short* __restrict__ ow,
                                                       const float* __restrict__ ob,
                                                       const float* __restrict__ x,
                                                       float* __restrict__ out) {
    __shared__ GemmLds lds;
    floatx4 acc[4][4];
    const int m0 = blockIdx.x * 128, n0 = blockIdx.y * 128;
    gemm_bt_core(oe, ow, E_DIMC, E_DIMC, E_DIMC, m0, n0, lds, acc);

    const int tid = threadIdx.x, lane = tid & 63, wave = tid >> 6;
    const int quad = lane >> 4, l16 = lane & 15;
    const int wm = (wave >> 1) * 64, wn = (wave & 1) * 64;
    #pragma unroll
    for (int mt = 0; mt < 4; mt++)
        #pragma unroll
        for (int nt = 0; nt < 4; nt++)
            #pragma unroll
            for (int r = 0; r < 4; r++) {
                int m = m0 + wm + mt * 16 + quad * 4 + r;
                int n = n0 + wn + nt * 16 + l16;
                size_t off = (size_t)m * H_DIM + n;
                out[off] = acc[mt][nt][r] + ob[n] + x[off];
            }
}

// ---------------------------------------------------------------------------
extern "C" void kernel_launch(void* const* d_in, const int* in_sizes, int n_in,
                              void* d_out, int out_size, void* d_ws, size_t ws_size,
                              hipStream_t stream) {
    const float* x     = (const float*)d_in[0];
    const float* ln_g  = (const float*)d_in[1];
    const float* uv_w  = (const float*)d_in[2];
    const float* uv_b  = (const float*)d_in[3];
    const float* gamma = (const float*)d_in[4];
    const float* beta  = (const float*)d_in[5];
    const float* wbias = (const float*)d_in[6];
    const float* o_w   = (const float*)d_in[7];
    const float* o_b   = (const float*)d_in[8];
    float* out = (float*)d_out;

    char* ws = (char*)d_ws;
    size_t off = 0;
    auto alloc = [&](size_t bytes) {
        void* p = ws + off;
        off += (bytes + 255) & ~(size_t)255;
        return p;
    };
    // Peak ~196.4 MiB:
    unsigned short* u     = (unsigned short*)alloc((size_t)M_TOT * E_DIMC * 2);      // 64 MiB (u, then oe in place)
    unsigned short* vT    = (unsigned short*)alloc((size_t)64 * E_DIMC * S_LEN * 2); // 64 MiB
    unsigned short* xn    = (unsigned short*)alloc((size_t)M_TOT * H_DIM * 2);       // 32 MiB
    unsigned short* P     = xn;                                                      // alias (xn dead after gemm1)
    float*          base  = (float*)alloc((size_t)M_TOT * D_DIM * 4);                // 16 MiB
    unsigned short* q     = (unsigned short*)alloc((size_t)M_TOT * D_DIM * 2);       // 8 MiB
    unsigned short* k     = (unsigned short*)alloc((size_t)M_TOT * D_DIM * 2);       // 8 MiB
    float*          cost  = (float*)alloc((size_t)S_LEN * 64 * 4);
    float*          sint  = (float*)alloc((size_t)S_LEN * 64 * 4);
    unsigned short* uvwb  = (unsigned short*)alloc((size_t)UV_DIM * H_DIM * 2);      // 2.2 MiB
    unsigned short* owb   = (unsigned short*)alloc((size_t)H_DIM * E_DIMC * 2);      // 1 MiB
    (void)ws_size; (void)in_sizes; (void)n_in; (void)out_size;

    f2bf_kernel<<<(UV_DIM * H_DIM / 4 + 255) / 256, 256, 0, stream>>>(uv_w, uvwb, UV_DIM * H_DIM / 4);
    f2bf_kernel<<<(H_DIM * E_DIMC / 4 + 255) / 256, 256, 0, stream>>>(o_w, owb, H_DIM * E_DIMC / 4);
    rope_table_kernel<<<S_LEN, 64, 0, stream>>>(cost, sint);

    rmsnorm_kernel<<<M_TOT / 4, 256, 0, stream>>>(x, ln_g, xn);

    // gemm1 + silu; writes u, vT (transposed), base
    gemm1_kernel<<<dim3(M_TOT / 128, UV_DIM / 128), 256, 0, stream>>>(xn, uvwb, uv_b, u, vT, base);

    rope_apply_kernel<<<M_TOT * 64 / 256, 256, 0, stream>>>(base, gamma, beta, cost, sint, q, k);

    // P = relu^2((q k^T + bias)/sqrt(128))   (overwrites xn region)
    gemm_qk_kernel<<<dim3(S_LEN / 128, S_LEN / 128, 64), 256, 0, stream>>>(q, k, wbias, P);

    // u <- u .* (P @ v)  in place
    gemm_pv_kernel<<<dim3(S_LEN / 128, E_DIMC / 128, 64), 256, 0, stream>>>(P, vT, u);

    // out = oe @ o_w^T + o_b + x
    gemm_out_kernel<<<dim3(M_TOT / 128, H_DIM / 128), 256, 0, stream>>>(u, owb, o_b, x, out);
}